// Round 5
// baseline (484.357 us; speedup 1.0000x reference)
//
#include <hip/hip_runtime.h>
#include <math.h>

#define N_PIX 65536
#define EPSF 1e-6f
#define CHUNKS 16
#define PX_PER_CHUNK 4096   // 65536 / 16
#define PX_PER_WAVE 512     // 8 waves per block, 8 super-tiles of 64 px
#define N_JOBS 48           // 2 imgs * 8 batch * 3 channels

typedef __attribute__((ext_vector_type(2))) float f2;
using short8 = __attribute__((ext_vector_type(8))) short;
using f32x4  = __attribute__((ext_vector_type(4))) float;

__device__ __forceinline__ float rcp_fast(float x) { return __builtin_amdgcn_rcpf(x); }

// round-half-up bf16 pack: {lo=a, hi=b}. All inputs are positive finite, so
// +0x8000 then truncate is correct round-half-up (bias <= 1/2 ulp vs RNE).
__device__ __forceinline__ uint32_t pk_bf16_rhu(float a, float b) {
    const uint32_t ua = __builtin_bit_cast(uint32_t, a) + 0x8000u;
    const uint32_t ub = __builtin_bit_cast(uint32_t, b) + 0x8000u;
    return __builtin_amdgcn_perm(ub, ua, 0x07060302u);
}

// ---------------------------------------------------------------------------
// Kernel 1: per (job, chunk) 64x64 histogram contribution via bf16 MFMA with
// fragment-direct operand generation. 512 thr/block (8 waves) x 768 blocks =
// 3 blocks/CU, 6 waves/SIMD. Per wave (private padded 1.125KB LDS): phase A
// computes (u*50, v*50, w) per pixel (lane = pixel), prefetching the next
// tile's pixels; phase B: each lane evaluates exactly the RBF values its MFMA
// fragments need (A[m=l15][k=quad*8+j], 4 m-tiles) via broadcast ds_read_b128
// (quad stride 144B -> conflict-free) + rcp-of-product; 16 MFMA per K=32 half.
// Epilogue: 8-wave LDS reduce, then global atomicAdd into hist.
// ---------------------------------------------------------------------------
__global__ __launch_bounds__(512, 6) void hist_kernel(
    const float* __restrict__ x, const float* __restrict__ y,
    float* __restrict__ hist)
{
    const int blk = blockIdx.x;            // 0..767
    const int chunk = blk & (CHUNKS - 1);
    const int job = blk / CHUNKS;          // 0..47
    const int c = job % 3;
    const int ib = job / 3;                // img*8 + b
    const int img = ib >> 3;
    const int b = ib & 7;
    const float* __restrict__ src = (img == 0 ? x : y) + (size_t)b * 3 * N_PIX;

    __shared__ __align__(16) float lds[4608];   // 18 KB: 8 x 288-float wbufs / reduce
    const int tid = threadIdx.x;
    const int lane = tid & 63;
    const int wv = tid >> 6;
    float* __restrict__ wbuf = lds + wv * 288;  // 64 px * float4, +16B pad per 8 px

    const int quad = lane >> 4;
    const int l15 = lane & 15;
    // negated scaled centers for this lane's 4 m-rows: -(c_m * 50), m = mt*16+l15
    f2 ncb01, ncb23;
    {
        const float c0 = (-3.0f + (float)(l15)      * (6.0f / 63.0f)) * 50.0f;
        const float c1 = (-3.0f + (float)(16 + l15) * (6.0f / 63.0f)) * 50.0f;
        const float c2 = (-3.0f + (float)(32 + l15) * (6.0f / 63.0f)) * 50.0f;
        const float c3 = (-3.0f + (float)(48 + l15) * (6.0f / 63.0f)) * 50.0f;
        ncb01 = (f2){-c0, -c1};
        ncb23 = (f2){-c2, -c3};
    }
    const f2 one2 = {1.0f, 1.0f};

    f32x4 acc[16];                         // acc[mt*4+nt]
#pragma unroll
    for (int i = 0; i < 16; ++i) acc[i] = (f32x4){0.f, 0.f, 0.f, 0.f};

    const int px0 = chunk * PX_PER_CHUNK + wv * PX_PER_WAVE;

    // prefetch super-tile 0
    float pr = src[px0 + lane];
    float pg = src[N_PIX + px0 + lane];
    float pb = src[2 * N_PIX + px0 + lane];

    for (int st = 0; st < PX_PER_WAVE / 64; ++st) {   // 8 super-tiles of 64 px
        // ---- Phase A: one pixel per lane ----
        const float r  = pr + EPSF;
        const float g  = pg + EPSF;
        const float bl = pb + EPSF;
        if (st < PX_PER_WAVE / 64 - 1) {              // prefetch next tile
            const int n2 = px0 + (st + 1) * 64 + lane;
            pr = src[n2]; pg = src[N_PIX + n2]; pb = src[2 * N_PIX + n2];
        }
        const float wgt = sqrtf(fmaf(r, r, fmaf(g, g, bl * bl)));
        const float lr = __logf(r), lg = __logf(g), lb2 = __logf(bl);
        // channel c: u = l_c - l_a, v = l_c - l_b;  c0:(a,b)=(g,b) c1:(r,b) c2:(r,g)
        const float l0 = (c == 0) ? lr : ((c == 1) ? lg : lb2);
        const float lu = (c == 0) ? lg : lr;
        const float lv = (c == 2) ? lg : lb2;
        const float4 uvw = make_float4((l0 - lu) * 50.0f, (l0 - lv) * 50.0f, wgt, 0.0f);
        // padded store: +4 floats per 8-px group -> quad read stride 144B
        *(float4*)(wbuf + lane * 4 + (lane >> 3) * 4) = uvw;   // same-wave DS, no barrier

#pragma unroll
        for (int h = 0; h < 2; ++h) {              // two K=32 halves
            const int base = h * 32 + quad * 8;    // first pixel this lane consumes
            const float4* __restrict__ pbase =
                (const float4*)(wbuf + base * 4 + (base >> 3) * 4);
            int aU[4][4], aV[4][4];                // fragment words [mt][jp]

#pragma unroll
            for (int jp = 0; jp < 4; ++jp) {       // j = 2jp (even), 2jp+1 (odd)
                const float4 pe = pbase[2 * jp];
                const float4 po = pbase[2 * jp + 1];

                float aue[4], auo[4], bve[4], bvo[4];
#pragma unroll
                for (int eo = 0; eo < 2; ++eo) {
                    const float ru = eo ? po.x : pe.x;
                    const float rv = eo ? po.y : pe.y;
                    const float rw = eo ? po.z : pe.z;
                    float* au = eo ? auo : aue;
                    float* bv = eo ? bvo : bve;

                    const f2 ruu = {ru, ru};
                    const f2 tu01 = ruu + ncb01;
                    const f2 tu23 = ruu + ncb23;
                    const f2 qu01 = __builtin_elementwise_fma(tu01, tu01, one2);
                    const f2 qu23 = __builtin_elementwise_fma(tu23, tu23, one2);
                    // rcp of product: 1 rcp serves 2 denominators (err ~3 ulp fp32)
                    const float Ru0 = rcp_fast(qu01.x * qu01.y) * rw;
                    const float Ru1 = rcp_fast(qu23.x * qu23.y) * rw;
                    au[0] = Ru0 * qu01.y; au[1] = Ru0 * qu01.x;
                    au[2] = Ru1 * qu23.y; au[3] = Ru1 * qu23.x;

                    const f2 rvv = {rv, rv};
                    const f2 tv01 = rvv + ncb01;
                    const f2 tv23 = rvv + ncb23;
                    const f2 qv01 = __builtin_elementwise_fma(tv01, tv01, one2);
                    const f2 qv23 = __builtin_elementwise_fma(tv23, tv23, one2);
                    const float Rv0 = rcp_fast(qv01.x * qv01.y);
                    const float Rv1 = rcp_fast(qv23.x * qv23.y);
                    bv[0] = Rv0 * qv01.y; bv[1] = Rv0 * qv01.x;
                    bv[2] = Rv1 * qv23.y; bv[3] = Rv1 * qv23.x;
                }
#pragma unroll
                for (int mt = 0; mt < 4; ++mt) {
                    aU[mt][jp] = pk_bf16_rhu(aue[mt], auo[mt]);
                    aV[mt][jp] = pk_bf16_rhu(bve[mt], bvo[mt]);
                }
            }

            short8 af[4], bf[4];
#pragma unroll
            for (int mt = 0; mt < 4; ++mt) {
                af[mt] = __builtin_bit_cast(short8,
                    make_int4(aU[mt][0], aU[mt][1], aU[mt][2], aU[mt][3]));
                bf[mt] = __builtin_bit_cast(short8,
                    make_int4(aV[mt][0], aV[mt][1], aV[mt][2], aV[mt][3]));
            }
#pragma unroll
            for (int mt = 0; mt < 4; ++mt)
#pragma unroll
                for (int nt = 0; nt < 4; ++nt)
                    acc[mt * 4 + nt] = __builtin_amdgcn_mfma_f32_16x16x32_bf16(
                        af[mt], bf[nt], acc[mt * 4 + nt], 0, 0, 0);
        }
    }

    // ---- Block-reduce the 8 waves, then atomic-add into global hist ----
    __syncthreads();
    for (int i = tid; i < 4096; i += 512) lds[i] = 0.0f;
    __syncthreads();
#pragma unroll
    for (int mt = 0; mt < 4; ++mt)
#pragma unroll
        for (int nt = 0; nt < 4; ++nt)
#pragma unroll
            for (int i = 0; i < 4; ++i) {
                const int m = mt * 16 + quad * 4 + i;   // C/D: row = quad*4+reg
                const int nn = nt * 16 + l15;           //      col = lane&15
                atomicAdd(&lds[m * 64 + nn], acc[mt * 4 + nt][i]);
            }
    __syncthreads();

    float* __restrict__ hj = hist + (size_t)job * 4096;
    for (int i = tid; i < 4096; i += 512) atomicAdd(&hj[i], lds[i]);
}

// ---------------------------------------------------------------------------
// Kernel 2: per-batch normalization + Hellinger distance; each block adds its
// batch's sqrt(0.5*h)/8 into out[0] (out zeroed by memset beforehand).
// ---------------------------------------------------------------------------
__global__ __launch_bounds__(1024) void loss_kernel(
    const float* __restrict__ hist, float* __restrict__ out)
{
    const int b = blockIdx.x;  // 0..7
    __shared__ float red[16];
    const int tid = threadIdx.x;
    const int wv = tid >> 6;
    const float* xh = hist + (size_t)(b * 3) * 4096;        // img 0, batch b
    const float* yh = hist + (size_t)((8 + b) * 3) * 4096;  // img 1, batch b

    float sx = 0.0f, sy = 0.0f;
    for (int i = tid; i < 3 * 4096; i += 1024) { sx += xh[i]; sy += yh[i]; }
    float v = sx;
#pragma unroll
    for (int o = 32; o > 0; o >>= 1) v += __shfl_down(v, o, 64);
    if ((tid & 63) == 0) red[wv] = v;
    __syncthreads();
    float tx = 0.0f;
#pragma unroll
    for (int i = 0; i < 16; ++i) tx += red[i];
    __syncthreads();
    v = sy;
#pragma unroll
    for (int o = 32; o > 0; o >>= 1) v += __shfl_down(v, o, 64);
    if ((tid & 63) == 0) red[wv] = v;
    __syncthreads();
    float ty = 0.0f;
#pragma unroll
    for (int i = 0; i < 16; ++i) ty += red[i];
    __syncthreads();

    const float invx = 1.0f / tx, invy = 1.0f / ty;
    float h = 0.0f;
    for (int i = tid; i < 3 * 4096; i += 1024) {
        const float d = sqrtf(yh[i] * invy) - sqrtf(xh[i] * invx);
        h = fmaf(d, d, h);
    }
#pragma unroll
    for (int o = 32; o > 0; o >>= 1) h += __shfl_down(h, o, 64);
    if ((tid & 63) == 0) red[wv] = h;
    __syncthreads();
    if (tid == 0) {
        float hs = 0.0f;
#pragma unroll
        for (int i = 0; i < 16; ++i) hs += red[i];
        atomicAdd(out, sqrtf(0.5f * hs) * 0.125f);
    }
}

extern "C" void kernel_launch(void* const* d_in, const int* in_sizes, int n_in,
                              void* d_out, int out_size, void* d_ws, size_t ws_size,
                              hipStream_t stream)
{
    const float* x = (const float*)d_in[0];
    const float* y = (const float*)d_in[1];
    float* ws = (float*)d_ws;
    float* hist = ws;                                  // 48*4096 floats (786 KB)
    float* outf = (float*)d_out;

    hipMemsetAsync(hist, 0, (size_t)N_JOBS * 4096 * sizeof(float), stream);
    hipMemsetAsync(outf, 0, sizeof(float), stream);
    hipLaunchKernelGGL(hist_kernel, dim3(N_JOBS * CHUNKS), dim3(512), 0, stream,
                       x, y, hist);
    hipLaunchKernelGGL(loss_kernel, dim3(8), dim3(1024), 0, stream, hist, outf);
}

// Round 6
// 263.248 us; speedup vs baseline: 1.8399x; 1.8399x over previous
//
#include <hip/hip_runtime.h>
#include <math.h>

#define N_PIX 65536
#define EPSF 1e-6f
#define CHUNKS 32
#define PX_PER_CHUNK 2048   // 65536 / 32
#define PX_PER_WAVE 512     // 4 waves per block, 8 super-tiles of 64 px
#define N_JOBS 48           // 2 imgs * 8 batch * 3 channels

typedef __attribute__((ext_vector_type(2))) float f2;
using short8 = __attribute__((ext_vector_type(8))) short;
using f32x4  = __attribute__((ext_vector_type(4))) float;

__device__ __forceinline__ float rcp_fast(float x) { return __builtin_amdgcn_rcpf(x); }

// round-half-up bf16 pack: {lo=a, hi=b}. All inputs are positive finite, so
// +0x8000 then truncate is correct round-half-up (bias <= 1/2 ulp vs RNE).
__device__ __forceinline__ uint32_t pk_bf16_rhu(float a, float b) {
    const uint32_t ua = __builtin_bit_cast(uint32_t, a) + 0x8000u;
    const uint32_t ub = __builtin_bit_cast(uint32_t, b) + 0x8000u;
    return __builtin_amdgcn_perm(ub, ua, 0x07060302u);
}

// ---------------------------------------------------------------------------
// Kernel 1: per (job, chunk) 64x64 histogram contribution via bf16 MFMA with
// fragment-direct operand generation. 256 thr/block (4 waves) x 1536 blocks =
// 6 blocks/CU = 6 waves/SIMD (R5's 512-thr + min-6-waves bound spilled the
// accumulators to scratch: VGPR 40, 1.3 GB scratch traffic — never again).
// Per wave (private padded 1.125KB LDS): phase A computes (u*50, v*50, w) per
// pixel (lane = pixel), prefetching the next tile's pixels; phase B: each lane
// evaluates exactly the RBF values its MFMA fragments need
// (A[m=l15][k=quad*8+j], 4 m-tiles) via broadcast ds_read_b128 (quad stride
// 144B -> conflict-free, verified R5: SQ_LDS_BANK_CONFLICT=0) +
// rcp-of-product; 16 MFMA per K=32 half.
// Epilogue: 4-wave LDS reduce, then global atomicAdd into hist.
// ---------------------------------------------------------------------------
__global__ __launch_bounds__(256, 4) void hist_kernel(
    const float* __restrict__ x, const float* __restrict__ y,
    float* __restrict__ hist)
{
    const int blk = blockIdx.x;            // 0..1535
    const int chunk = blk & (CHUNKS - 1);
    const int job = blk / CHUNKS;          // 0..47
    const int c = job % 3;
    const int ib = job / 3;                // img*8 + b
    const int img = ib >> 3;
    const int b = ib & 7;
    const float* __restrict__ src = (img == 0 ? x : y) + (size_t)b * 3 * N_PIX;

    __shared__ __align__(16) float lds[4096];   // 16 KB: 4 x 288-float wbufs / reduce
    const int tid = threadIdx.x;
    const int lane = tid & 63;
    const int wv = tid >> 6;
    float* __restrict__ wbuf = lds + wv * 288;  // 64 px * float4, +16B pad per 8 px

    const int quad = lane >> 4;
    const int l15 = lane & 15;
    // negated scaled centers for this lane's 4 m-rows: -(c_m * 50), m = mt*16+l15
    f2 ncb01, ncb23;
    {
        const float c0 = (-3.0f + (float)(l15)      * (6.0f / 63.0f)) * 50.0f;
        const float c1 = (-3.0f + (float)(16 + l15) * (6.0f / 63.0f)) * 50.0f;
        const float c2 = (-3.0f + (float)(32 + l15) * (6.0f / 63.0f)) * 50.0f;
        const float c3 = (-3.0f + (float)(48 + l15) * (6.0f / 63.0f)) * 50.0f;
        ncb01 = (f2){-c0, -c1};
        ncb23 = (f2){-c2, -c3};
    }
    const f2 one2 = {1.0f, 1.0f};

    f32x4 acc[16];                         // acc[mt*4+nt]
#pragma unroll
    for (int i = 0; i < 16; ++i) acc[i] = (f32x4){0.f, 0.f, 0.f, 0.f};

    const int px0 = chunk * PX_PER_CHUNK + wv * PX_PER_WAVE;

    // prefetch super-tile 0
    float pr = src[px0 + lane];
    float pg = src[N_PIX + px0 + lane];
    float pb = src[2 * N_PIX + px0 + lane];

    for (int st = 0; st < PX_PER_WAVE / 64; ++st) {   // 8 super-tiles of 64 px
        // ---- Phase A: one pixel per lane ----
        const float r  = pr + EPSF;
        const float g  = pg + EPSF;
        const float bl = pb + EPSF;
        if (st < PX_PER_WAVE / 64 - 1) {              // prefetch next tile
            const int n2 = px0 + (st + 1) * 64 + lane;
            pr = src[n2]; pg = src[N_PIX + n2]; pb = src[2 * N_PIX + n2];
        }
        const float wgt = sqrtf(fmaf(r, r, fmaf(g, g, bl * bl)));
        const float lr = __logf(r), lg = __logf(g), lb2 = __logf(bl);
        // channel c: u = l_c - l_a, v = l_c - l_b;  c0:(a,b)=(g,b) c1:(r,b) c2:(r,g)
        const float l0 = (c == 0) ? lr : ((c == 1) ? lg : lb2);
        const float lu = (c == 0) ? lg : lr;
        const float lv = (c == 2) ? lg : lb2;
        const float4 uvw = make_float4((l0 - lu) * 50.0f, (l0 - lv) * 50.0f, wgt, 0.0f);
        // padded store: +4 floats per 8-px group -> quad read stride 144B
        *(float4*)(wbuf + lane * 4 + (lane >> 3) * 4) = uvw;   // same-wave DS, no barrier

#pragma unroll
        for (int h = 0; h < 2; ++h) {              // two K=32 halves
            const int base = h * 32 + quad * 8;    // first pixel this lane consumes
            const float4* __restrict__ pbase =
                (const float4*)(wbuf + base * 4 + (base >> 3) * 4);
            int aU[4][4], aV[4][4];                // fragment words [mt][jp]

#pragma unroll
            for (int jp = 0; jp < 4; ++jp) {       // j = 2jp (even), 2jp+1 (odd)
                const float4 pe = pbase[2 * jp];
                const float4 po = pbase[2 * jp + 1];

                float aue[4], auo[4], bve[4], bvo[4];
#pragma unroll
                for (int eo = 0; eo < 2; ++eo) {
                    const float ru = eo ? po.x : pe.x;
                    const float rv = eo ? po.y : pe.y;
                    const float rw = eo ? po.z : pe.z;
                    float* au = eo ? auo : aue;
                    float* bv = eo ? bvo : bve;

                    const f2 ruu = {ru, ru};
                    const f2 tu01 = ruu + ncb01;
                    const f2 tu23 = ruu + ncb23;
                    const f2 qu01 = __builtin_elementwise_fma(tu01, tu01, one2);
                    const f2 qu23 = __builtin_elementwise_fma(tu23, tu23, one2);
                    // rcp of product: 1 rcp serves 2 denominators (err ~3 ulp fp32)
                    const float Ru0 = rcp_fast(qu01.x * qu01.y) * rw;
                    const float Ru1 = rcp_fast(qu23.x * qu23.y) * rw;
                    au[0] = Ru0 * qu01.y; au[1] = Ru0 * qu01.x;
                    au[2] = Ru1 * qu23.y; au[3] = Ru1 * qu23.x;

                    const f2 rvv = {rv, rv};
                    const f2 tv01 = rvv + ncb01;
                    const f2 tv23 = rvv + ncb23;
                    const f2 qv01 = __builtin_elementwise_fma(tv01, tv01, one2);
                    const f2 qv23 = __builtin_elementwise_fma(tv23, tv23, one2);
                    const float Rv0 = rcp_fast(qv01.x * qv01.y);
                    const float Rv1 = rcp_fast(qv23.x * qv23.y);
                    bv[0] = Rv0 * qv01.y; bv[1] = Rv0 * qv01.x;
                    bv[2] = Rv1 * qv23.y; bv[3] = Rv1 * qv23.x;
                }
#pragma unroll
                for (int mt = 0; mt < 4; ++mt) {
                    aU[mt][jp] = pk_bf16_rhu(aue[mt], auo[mt]);
                    aV[mt][jp] = pk_bf16_rhu(bve[mt], bvo[mt]);
                }
            }

            short8 af[4], bf[4];
#pragma unroll
            for (int mt = 0; mt < 4; ++mt) {
                af[mt] = __builtin_bit_cast(short8,
                    make_int4(aU[mt][0], aU[mt][1], aU[mt][2], aU[mt][3]));
                bf[mt] = __builtin_bit_cast(short8,
                    make_int4(aV[mt][0], aV[mt][1], aV[mt][2], aV[mt][3]));
            }
#pragma unroll
            for (int mt = 0; mt < 4; ++mt)
#pragma unroll
                for (int nt = 0; nt < 4; ++nt)
                    acc[mt * 4 + nt] = __builtin_amdgcn_mfma_f32_16x16x32_bf16(
                        af[mt], bf[nt], acc[mt * 4 + nt], 0, 0, 0);
        }
    }

    // ---- Block-reduce the 4 waves, then atomic-add into global hist ----
    __syncthreads();
    for (int i = tid; i < 4096; i += 256) lds[i] = 0.0f;
    __syncthreads();
#pragma unroll
    for (int mt = 0; mt < 4; ++mt)
#pragma unroll
        for (int nt = 0; nt < 4; ++nt)
#pragma unroll
            for (int i = 0; i < 4; ++i) {
                const int m = mt * 16 + quad * 4 + i;   // C/D: row = quad*4+reg
                const int nn = nt * 16 + l15;           //      col = lane&15
                atomicAdd(&lds[m * 64 + nn], acc[mt * 4 + nt][i]);
            }
    __syncthreads();

    float* __restrict__ hj = hist + (size_t)job * 4096;
    for (int i = tid; i < 4096; i += 256) atomicAdd(&hj[i], lds[i]);
}

// ---------------------------------------------------------------------------
// Kernel 2: per-batch normalization + Hellinger distance; each block adds its
// batch's sqrt(0.5*h)/8 into out[0] (out zeroed by memset beforehand).
// ---------------------------------------------------------------------------
__global__ __launch_bounds__(1024) void loss_kernel(
    const float* __restrict__ hist, float* __restrict__ out)
{
    const int b = blockIdx.x;  // 0..7
    __shared__ float red[16];
    const int tid = threadIdx.x;
    const int wv = tid >> 6;
    const float* xh = hist + (size_t)(b * 3) * 4096;        // img 0, batch b
    const float* yh = hist + (size_t)((8 + b) * 3) * 4096;  // img 1, batch b

    float sx = 0.0f, sy = 0.0f;
    for (int i = tid; i < 3 * 4096; i += 1024) { sx += xh[i]; sy += yh[i]; }
    float v = sx;
#pragma unroll
    for (int o = 32; o > 0; o >>= 1) v += __shfl_down(v, o, 64);
    if ((tid & 63) == 0) red[wv] = v;
    __syncthreads();
    float tx = 0.0f;
#pragma unroll
    for (int i = 0; i < 16; ++i) tx += red[i];
    __syncthreads();
    v = sy;
#pragma unroll
    for (int o = 32; o > 0; o >>= 1) v += __shfl_down(v, o, 64);
    if ((tid & 63) == 0) red[wv] = v;
    __syncthreads();
    float ty = 0.0f;
#pragma unroll
    for (int i = 0; i < 16; ++i) ty += red[i];
    __syncthreads();

    const float invx = 1.0f / tx, invy = 1.0f / ty;
    float h = 0.0f;
    for (int i = tid; i < 3 * 4096; i += 1024) {
        const float d = sqrtf(yh[i] * invy) - sqrtf(xh[i] * invx);
        h = fmaf(d, d, h);
    }
#pragma unroll
    for (int o = 32; o > 0; o >>= 1) h += __shfl_down(h, o, 64);
    if ((tid & 63) == 0) red[wv] = h;
    __syncthreads();
    if (tid == 0) {
        float hs = 0.0f;
#pragma unroll
        for (int i = 0; i < 16; ++i) hs += red[i];
        atomicAdd(out, sqrtf(0.5f * hs) * 0.125f);
    }
}

extern "C" void kernel_launch(void* const* d_in, const int* in_sizes, int n_in,
                              void* d_out, int out_size, void* d_ws, size_t ws_size,
                              hipStream_t stream)
{
    const float* x = (const float*)d_in[0];
    const float* y = (const float*)d_in[1];
    float* ws = (float*)d_ws;
    float* hist = ws;                                  // 48*4096 floats (786 KB)
    float* outf = (float*)d_out;

    hipMemsetAsync(hist, 0, (size_t)N_JOBS * 4096 * sizeof(float), stream);
    hipMemsetAsync(outf, 0, sizeof(float), stream);
    hipLaunchKernelGGL(hist_kernel, dim3(N_JOBS * CHUNKS), dim3(256), 0, stream,
                       x, y, hist);
    hipLaunchKernelGGL(loss_kernel, dim3(8), dim3(1024), 0, stream, hist, outf);
}